// Round 8
// baseline (214.611 us; speedup 1.0000x reference)
//
#include <hip/hip_runtime.h>
#include <hip/hip_cooperative_groups.h>

namespace cg = cooperative_groups;

// Chamfer min-matching loss, B=8, P=4096, D=2, fp32 — ONE cooperative dispatch.
// d2(q,g) = |q|^2 + (|g|^2 - 2 q.g); hx=-2gx, hy=-2gy, c=|g|^2 staged in LDS.
// Phase 1 = R6's proven named-scalar body (QPT=16): 2 fma + 0.5 min3 per pair.
// grid.sync. Phase 2a: cross-chunk min + sqrt + per-block sums. grid.sync.
// Phase 2b: block 0 reduces. R5 lesson: NO per-thread arrays (scratch spill);
// R7 lesson: ~7 us per dispatch -> single dispatch is the lever.

#define NB    8
#define NP    4096
#define NC    32
#define QPT   16
#define CHUNK (NP / NC)        // 128
#define GRID  (2 * NB * NC)    // 512 blocks, 2/CU co-resident guaranteed

typedef float f32x4 __attribute__((ext_vector_type(4)));

#define FOREACH_Q(M) M(0) M(1) M(2) M(3) M(4) M(5) M(6) M(7) \
                     M(8) M(9) M(10) M(11) M(12) M(13) M(14) M(15)

__global__ __launch_bounds__(256, 2) void chamferFused(const float* __restrict__ pred,
                                                       const float* __restrict__ gt,
                                                       float* __restrict__ pm,
                                                       float* __restrict__ bsum,
                                                       float* __restrict__ out) {
    __shared__ __align__(16) float shx[CHUNK];
    __shared__ __align__(16) float shy[CHUNK];
    __shared__ __align__(16) float sc[CHUNK];
    __shared__ float red[256];
    __shared__ float wsum2[2];

    cg::grid_group grid = cg::this_grid();

    int bid = blockIdx.x;
    int t   = threadIdx.x;

    // ---- Phase 1: per-(dir,b,chunk) partial mins for all 4096 queries ----
    {
        int gc  = bid & (NC - 1);
        int b   = (bid >> 5) & 7;
        int dir = bid >> 8;

        const float* query = dir ? gt : pred;
        const float* base  = dir ? pred : gt;

        const float2* base2 = (const float2*)base + (size_t)b * NP + gc * CHUNK;
        if (t < CHUNK) {
            float2 g = base2[t];
            shx[t] = -2.0f * g.x;
            shy[t] = -2.0f * g.y;
            sc[t]  = g.x * g.x + g.y * g.y;
        }
        __syncthreads();

        const float2* query2 = (const float2*)query + (size_t)b * NP;
        const float INF = 3.402823466e+38f;

#define DECLQ(k) float px##k, py##k, m##k = INF; \
        { float2 q_ = query2[t + (k) * 256]; px##k = q_.x; py##k = q_.y; }
        FOREACH_Q(DECLQ)
#undef DECLQ

        const f32x4* hx4 = (const f32x4*)shx;
        const f32x4* hy4 = (const f32x4*)shy;
        const f32x4* cc4 = (const f32x4*)sc;

#pragma unroll 4
        for (int j = 0; j < CHUNK / 4; ++j) {
            f32x4 hx = hx4[j], hy = hy4[j], cc = cc4[j];
#define STEP(k) { \
            float d0_ = fmaf(px##k, hx.x, fmaf(py##k, hy.x, cc.x)); \
            float d1_ = fmaf(px##k, hx.y, fmaf(py##k, hy.y, cc.y)); \
            float d2_ = fmaf(px##k, hx.z, fmaf(py##k, hy.z, cc.z)); \
            float d3_ = fmaf(px##k, hx.w, fmaf(py##k, hy.w, cc.w)); \
            m##k = fminf(fminf(m##k, d0_), d1_);   /* v_min3_f32 */ \
            m##k = fminf(fminf(m##k, d2_), d3_); }
            FOREACH_Q(STEP)
#undef STEP
        }

        float* slot = pm + (((size_t)dir * NB + b) * NC + gc) * NP + t;
#define STORE(k) slot[(k) * 256] = fmaf(px##k, px##k, fmaf(py##k, py##k, m##k));
        FOREACH_Q(STORE)
#undef STORE
    }

    __threadfence();
    grid.sync();

    // ---- Phase 2a: cross-chunk min + sqrt + per-block partial sum ----
    {
        int s    = bid * 128 + (t & 127);   // query slot, 512*128 = 65536
        int dirb = s >> 12;                 // dir*NB + b
        int q    = s & (NP - 1);
        int half = t >> 7;                  // 0,1 -> chunks [0,16) / [16,32)

        const float* p = pm + ((size_t)dirb * NC + half * 16) * NP + q;
        float mv = p[0];
#pragma unroll
        for (int c = 1; c < 16; ++c) mv = fminf(mv, p[(size_t)c * NP]);
        red[t] = mv;
        __syncthreads();

        if (t < 128) {
            float m2 = fminf(red[t], red[t + 128]);
            float v = sqrtf(fmaxf(m2, 1e-12f));
#pragma unroll
            for (int o = 32; o > 0; o >>= 1) v += __shfl_down(v, o, 64);
            if ((t & 63) == 0) wsum2[t >> 6] = v;
        }
        __syncthreads();
        if (t == 0) bsum[bid] = wsum2[0] + wsum2[1];
    }

    __threadfence();
    grid.sync();

    // ---- Phase 2b: block 0 reduces 512 partials ----
    if (bid == 0) {
        float s = bsum[t] + bsum[t + 256];
#pragma unroll
        for (int o = 32; o > 0; o >>= 1) s += __shfl_down(s, o, 64);
        __shared__ float wsum[4];
        int lane = t & 63, w = t >> 6;
        if (lane == 0) wsum[w] = s;
        __syncthreads();
        if (t == 0)
            *out = ((wsum[0] + wsum[1]) + (wsum[2] + wsum[3])) * (0.5f / (float)(NB * NP));
    }
}

extern "C" void kernel_launch(void* const* d_in, const int* in_sizes, int n_in,
                              void* d_out, int out_size, void* d_ws, size_t ws_size,
                              hipStream_t stream) {
    const float* pred = (const float*)d_in[0];
    const float* gt   = (const float*)d_in[1];
    float*       out  = (float*)d_out;
    float*       pm   = (float*)d_ws;                       // 8 MiB
    float*       bsum = pm + (size_t)2 * NB * NC * NP;      // 512 f32

    (void)in_sizes; (void)n_in; (void)out_size; (void)ws_size;

    void* args[] = { (void*)&pred, (void*)&gt, (void*)&pm, (void*)&bsum, (void*)&out };
    hipLaunchCooperativeKernel((void*)chamferFused, dim3(GRID), dim3(256), args, 0, stream);
}

// Round 9
// 53.659 us; speedup vs baseline: 3.9995x; 3.9995x over previous
//
#include <hip/hip_runtime.h>

// Chamfer min-matching loss, B=8, P=4096, D=2, fp32 — exact NN via spatial binning.
// Kernel 1 (binSort, 16 blocks): per (batch, side) counting-sort of 4096 points
//   into 64x64 bins (LDS histogram + scan + scatter). Also zeroes out.
// Kernel 2 (binSearch, 256 blocks): per query, expanding-ring exact NN search
//   over the sorted target side. Ring r lower bound: any point in a bin at
//   Chebyshev ring r is >= (r-1)*H away (conservative under clamping: clamped
//   coords only move points OUTWARD -> true distance >= bound). Terminates by
//   r=64 (full grid coverage). Queries read from the SORTED array (mean is
//   order-invariant) -> adjacent lanes search adjacent regions.
// R5/R8 lessons: no cooperative launch, no per-thread runtime-indexed arrays.

#define NB    8
#define NP    4096
#define BINS  64
#define NBIN  (BINS * BINS)
#define H     0.15625f          // 10.0 / 64
#define XMIN  -5.0f
#define INVH  6.4f

__device__ __forceinline__ int binIdx(float x) {
    int i = (int)((x - XMIN) * INVH);
    return i < 0 ? 0 : (i > BINS - 1 ? BINS - 1 : i);
}

// ---- Kernel 1: counting sort, one block per (batch, side) ----
__global__ __launch_bounds__(256) void binSort(const float* __restrict__ pred,
                                               const float* __restrict__ gt,
                                               float2* __restrict__ P,      // [16][NP]
                                               unsigned* __restrict__ BS,   // [16][NBIN+1]
                                               float* __restrict__ out) {
    __shared__ unsigned cnt[NBIN];      // 16 KB
    __shared__ unsigned waveTot[4];

    int t   = threadIdx.x;
    int bid = blockIdx.x;               // 0..15:  b*2 + side
    int b = bid >> 1, side = bid & 1;

    if (bid == 0 && t == 0) *out = 0.0f;   // stream order: before binSearch atomics

    const float2* src = (const float2*)(side ? gt : pred) + (size_t)b * NP;
    float2*   dst = P  + (size_t)bid * NP;
    unsigned* bs  = BS + (size_t)bid * (NBIN + 1);

    // zero counts (thread t owns bins [t*16, t*16+16))
#pragma unroll
    for (int i = 0; i < 16; ++i) cnt[t * 16 + i] = 0;
    __syncthreads();

    // count
    for (int i = t; i < NP; i += 256) {
        float2 p = src[i];
        atomicAdd(&cnt[binIdx(p.x) * BINS + binIdx(p.y)], 1u);
    }
    __syncthreads();

    // exclusive scan over 4096 bins: per-thread sum of its 16 bins, then
    // wave-inclusive shfl scan, then cross-wave offsets, then write-back.
    unsigned local = 0;
#pragma unroll
    for (int i = 0; i < 16; ++i) local += cnt[t * 16 + i];

    unsigned inc = local;
#pragma unroll
    for (int o = 1; o < 64; o <<= 1) {
        unsigned n = __shfl_up(inc, o, 64);
        if ((t & 63) >= o) inc += n;
    }
    if ((t & 63) == 63) waveTot[t >> 6] = inc;
    __syncthreads();
    unsigned wbase = 0;
#pragma unroll
    for (int w = 0; w < 4; ++w) if (w < (t >> 6)) wbase += waveTot[w];
    unsigned run = wbase + inc - local;   // exclusive prefix for this thread's bins

#pragma unroll
    for (int i = 0; i < 16; ++i) {
        unsigned c = cnt[t * 16 + i];
        cnt[t * 16 + i] = run;            // cnt becomes bin starts
        run += c;
    }
    __syncthreads();

    // publish bin starts
    for (int i = t; i < NBIN; i += 256) bs[i] = cnt[i];
    if (t == 0) bs[NBIN] = NP;
    __syncthreads();                      // bs reads done before cursors mutate

    // scatter (cnt used as running cursors)
    for (int i = t; i < NP; i += 256) {
        float2 p = src[i];
        unsigned pos = atomicAdd(&cnt[binIdx(p.x) * BINS + binIdx(p.y)], 1u);
        dst[pos] = p;
    }
}

// ---- Kernel 2: expanding-ring exact NN search ----
__global__ __launch_bounds__(256) void binSearch(const float2* __restrict__ P,
                                                 const unsigned* __restrict__ BS,
                                                 float* __restrict__ out) {
    int t     = threadIdx.x;
    int bid   = blockIdx.x;        // 0..255
    int qs    = bid >> 4;          // dir*8 + b
    int slice = bid & 15;
    int b = qs & 7, dir = qs >> 3; // dir0: query=pred(side0), target=gt(side1)

    const float2*   qarr = P  + (size_t)(b * 2 + dir) * NP;
    int tgt = b * 2 + (1 - dir);
    const float2*   tp   = P  + (size_t)tgt * NP;
    const unsigned* bs   = BS + (size_t)tgt * (NBIN + 1);

    float2 q = qarr[slice * 256 + t];
    float qx = q.x, qy = q.y;
    int qi = binIdx(qx), qj = binIdx(qy);

    float best = 3.402823466e+38f;
    int r = 0;
    while (true) {
        int i0 = qi - r, i1 = qi + r, j0 = qj - r, j1 = qj + r;
        if (i0 < 0 && j0 < 0 && i1 >= BINS && j1 >= BINS) break;   // grid covered
        if (r >= 2) {
            float lb = (float)(r - 1) * H;
            if (lb * lb >= best) break;                            // no ring can beat
        }
        int ja = j0 < 0 ? 0 : j0, jb = j1 >= BINS ? BINS - 1 : j1;

        // top row (contiguous run of bins -> one candidate range)
        if (i0 >= 0) {
            unsigned s = bs[i0 * BINS + ja], e = bs[i0 * BINS + jb + 1];
            for (unsigned k = s; k < e; ++k) {
                float2 pt = tp[k];
                float dx = qx - pt.x, dy = qy - pt.y;
                best = fminf(best, fmaf(dx, dx, dy * dy));
            }
        }
        if (r > 0) {
            // bottom row
            if (i1 < BINS) {
                unsigned s = bs[i1 * BINS + ja], e = bs[i1 * BINS + jb + 1];
                for (unsigned k = s; k < e; ++k) {
                    float2 pt = tp[k];
                    float dx = qx - pt.x, dy = qy - pt.y;
                    best = fminf(best, fmaf(dx, dx, dy * dy));
                }
            }
            // side columns (excluding corners already scanned)
            int ia = (i0 + 1 < 0) ? 0 : i0 + 1;
            int ib = (i1 - 1 >= BINS) ? BINS - 1 : i1 - 1;
            if (j0 >= 0) {
                for (int ii = ia; ii <= ib; ++ii) {
                    unsigned s = bs[ii * BINS + j0], e = bs[ii * BINS + j0 + 1];
                    for (unsigned k = s; k < e; ++k) {
                        float2 pt = tp[k];
                        float dx = qx - pt.x, dy = qy - pt.y;
                        best = fminf(best, fmaf(dx, dx, dy * dy));
                    }
                }
            }
            if (j1 < BINS) {
                for (int ii = ia; ii <= ib; ++ii) {
                    unsigned s = bs[ii * BINS + j1], e = bs[ii * BINS + j1 + 1];
                    for (unsigned k = s; k < e; ++k) {
                        float2 pt = tp[k];
                        float dx = qx - pt.x, dy = qy - pt.y;
                        best = fminf(best, fmaf(dx, dx, dy * dy));
                    }
                }
            }
        }
        ++r;
    }

    float v = sqrtf(fmaxf(best, 1e-12f));

#pragma unroll
    for (int o = 32; o > 0; o >>= 1) v += __shfl_down(v, o, 64);

    __shared__ float wsum[4];
    if ((t & 63) == 0) wsum[t >> 6] = v;
    __syncthreads();
    if (t == 0)
        atomicAdd(out, ((wsum[0] + wsum[1]) + (wsum[2] + wsum[3])) *
                           (0.5f / (float)(NB * NP)));
}

extern "C" void kernel_launch(void* const* d_in, const int* in_sizes, int n_in,
                              void* d_out, int out_size, void* d_ws, size_t ws_size,
                              hipStream_t stream) {
    const float* pred = (const float*)d_in[0];
    const float* gt   = (const float*)d_in[1];
    float*       out  = (float*)d_out;

    float2*   P  = (float2*)d_ws;                       // 16 * 4096 * 8 B = 512 KB
    unsigned* BS = (unsigned*)(P + (size_t)16 * NP);    // 16 * 4097 * 4 B ≈ 262 KB

    (void)in_sizes; (void)n_in; (void)out_size; (void)ws_size;

    binSort<<<16, 256, 0, stream>>>(pred, gt, P, BS, out);
    binSearch<<<256, 256, 0, stream>>>(P, BS, out);
}

// Round 10
// 41.580 us; speedup vs baseline: 5.1614x; 1.2905x over previous
//
#include <hip/hip_runtime.h>

// Chamfer min-matching loss, B=8, P=4096, D=2, fp32 — exact NN via spatial
// binning, LDS-staged search.
// Kernel 1 (binSort, 16 blocks): counting-sort each (batch, side)'s 4096 pts
//   into 64x64 bins (LDS histogram + shfl scan + scatter).
// Kernel 2 (binSearch, 256 blocks): stage target side (sorted pts 32 KB +
//   bin starts 16 KB) into LDS via coalesced dwordx4, then expanding-ring
//   exact NN per query out of LDS. Ring bound (r-1)*H is conservative under
//   clamping (clamped coords only move points outward).
// R9 lesson: L2 dies at dispatch boundary; scattered HBM loads at 24 GB/s
//   were 40 us -> stage once, search in LDS.

#define NB    8
#define NP    4096
#define BINS  64
#define NBIN  (BINS * BINS)
#define H     0.15625f          // 10.0 / 64
#define XMIN  -5.0f
#define INVH  6.4f

__device__ __forceinline__ int binIdx(float x) {
    int i = (int)((x - XMIN) * INVH);
    return i < 0 ? 0 : (i > BINS - 1 ? BINS - 1 : i);
}

// ---- Kernel 1: counting sort, one block per (batch, side) ----
// Block s handles tgt = ((s&7)<<1)|(s>>3) so the sorter of target T lands on
// XCD (T>>1)%8 — same XCD group as T's searchers (bid%8 = b there).
__global__ __launch_bounds__(256) void binSort(const float* __restrict__ pred,
                                               const float* __restrict__ gt,
                                               float2* __restrict__ P,      // [16][NP]
                                               unsigned* __restrict__ BS,   // [16][NBIN+1]
                                               float* __restrict__ out) {
    __shared__ unsigned cnt[NBIN];      // 16 KB
    __shared__ unsigned waveTot[4];

    int t   = threadIdx.x;
    int s   = blockIdx.x;               // 0..15
    int tgt = ((s & 7) << 1) | (s >> 3);
    int b = tgt >> 1, side = tgt & 1;

    if (s == 0 && t == 0) *out = 0.0f;  // stream order: before binSearch atomics

    const float2* src = (const float2*)(side ? gt : pred) + (size_t)b * NP;
    float2*   dst = P  + (size_t)tgt * NP;
    unsigned* bs  = BS + (size_t)tgt * (NBIN + 1);

#pragma unroll
    for (int i = 0; i < 16; ++i) cnt[t * 16 + i] = 0;
    __syncthreads();

    for (int i = t; i < NP; i += 256) {
        float2 p = src[i];
        atomicAdd(&cnt[binIdx(p.x) * BINS + binIdx(p.y)], 1u);
    }
    __syncthreads();

    unsigned local = 0;
#pragma unroll
    for (int i = 0; i < 16; ++i) local += cnt[t * 16 + i];

    unsigned inc = local;
#pragma unroll
    for (int o = 1; o < 64; o <<= 1) {
        unsigned n = __shfl_up(inc, o, 64);
        if ((t & 63) >= o) inc += n;
    }
    if ((t & 63) == 63) waveTot[t >> 6] = inc;
    __syncthreads();
    unsigned wbase = 0;
#pragma unroll
    for (int w = 0; w < 4; ++w) if (w < (t >> 6)) wbase += waveTot[w];
    unsigned run = wbase + inc - local;

#pragma unroll
    for (int i = 0; i < 16; ++i) {
        unsigned c = cnt[t * 16 + i];
        cnt[t * 16 + i] = run;
        run += c;
    }
    __syncthreads();

    for (int i = t; i < NBIN; i += 256) bs[i] = cnt[i];
    if (t == 0) bs[NBIN] = NP;
    __syncthreads();

    for (int i = t; i < NP; i += 256) {
        float2 p = src[i];
        unsigned pos = atomicAdd(&cnt[binIdx(p.x) * BINS + binIdx(p.y)], 1u);
        dst[pos] = p;
    }
}

// ---- Kernel 2: LDS-staged expanding-ring exact NN search ----
// bid = slice*16 + qs: same-target blocks share bid mod 16 -> same XCD mod 8.
__global__ __launch_bounds__(256) void binSearch(const float2* __restrict__ P,
                                                 const unsigned* __restrict__ BS,
                                                 float* __restrict__ out) {
    __shared__ __align__(16) float2   sp[NP];        // 32 KB sorted target pts
    __shared__ __align__(16) unsigned sbs[NBIN + 4]; // 16 KB bin starts

    int t     = threadIdx.x;
    int bid   = blockIdx.x;        // 0..255
    int qs    = bid & 15;          // dir*8 + b
    int slice = bid >> 4;
    int b = qs & 7, dir = qs >> 3; // dir0: query=pred(side0), target=gt(side1)

    const float2* qarr = P + (size_t)(b * 2 + dir) * NP;
    int tgt = b * 2 + (1 - dir);
    const float2*   tp = P  + (size_t)tgt * NP;
    const unsigned* bs = BS + (size_t)tgt * (NBIN + 1);

    // stage target points + bin starts (coalesced dwordx4)
    const float4* tp4 = (const float4*)tp;
    float4*       sp4 = (float4*)sp;
#pragma unroll
    for (int i = 0; i < NP / 2 / 256; ++i) sp4[t + i * 256] = tp4[t + i * 256];
    const uint4* bs4  = (const uint4*)bs;
    uint4*       sbs4 = (uint4*)sbs;
#pragma unroll
    for (int i = 0; i < NBIN / 4 / 256; ++i) sbs4[t + i * 256] = bs4[t + i * 256];
    if (t == 0) sbs[NBIN] = NP;

    float2 q = qarr[slice * 256 + t];   // independent of LDS; issued pre-barrier
    __syncthreads();

    float qx = q.x, qy = q.y;
    int qi = binIdx(qx), qj = binIdx(qy);

    float best = 3.402823466e+38f;
    int r = 0;
    while (true) {
        int i0 = qi - r, i1 = qi + r, j0 = qj - r, j1 = qj + r;
        if (i0 < 0 && j0 < 0 && i1 >= BINS && j1 >= BINS) break;
        if (r >= 2) {
            float lb = (float)(r - 1) * H;
            if (lb * lb >= best) break;
        }
        int ja = j0 < 0 ? 0 : j0, jb = j1 >= BINS ? BINS - 1 : j1;

        if (i0 >= 0) {                      // top row: contiguous candidate run
            unsigned s = sbs[i0 * BINS + ja], e = sbs[i0 * BINS + jb + 1];
            for (unsigned k = s; k < e; ++k) {
                float2 pt = sp[k];
                float dx = qx - pt.x, dy = qy - pt.y;
                best = fminf(best, fmaf(dx, dx, dy * dy));
            }
        }
        if (r > 0) {
            if (i1 < BINS) {                // bottom row
                unsigned s = sbs[i1 * BINS + ja], e = sbs[i1 * BINS + jb + 1];
                for (unsigned k = s; k < e; ++k) {
                    float2 pt = sp[k];
                    float dx = qx - pt.x, dy = qy - pt.y;
                    best = fminf(best, fmaf(dx, dx, dy * dy));
                }
            }
            int ia = (i0 + 1 < 0) ? 0 : i0 + 1;
            int ib = (i1 - 1 >= BINS) ? BINS - 1 : i1 - 1;
            if (j0 >= 0) {                  // left column
                for (int ii = ia; ii <= ib; ++ii) {
                    unsigned s = sbs[ii * BINS + j0], e = sbs[ii * BINS + j0 + 1];
                    for (unsigned k = s; k < e; ++k) {
                        float2 pt = sp[k];
                        float dx = qx - pt.x, dy = qy - pt.y;
                        best = fminf(best, fmaf(dx, dx, dy * dy));
                    }
                }
            }
            if (j1 < BINS) {                // right column
                for (int ii = ia; ii <= ib; ++ii) {
                    unsigned s = sbs[ii * BINS + j1], e = sbs[ii * BINS + j1 + 1];
                    for (unsigned k = s; k < e; ++k) {
                        float2 pt = sp[k];
                        float dx = qx - pt.x, dy = qy - pt.y;
                        best = fminf(best, fmaf(dx, dx, dy * dy));
                    }
                }
            }
        }
        ++r;
    }

    float v = sqrtf(fmaxf(best, 1e-12f));

#pragma unroll
    for (int o = 32; o > 0; o >>= 1) v += __shfl_down(v, o, 64);

    __shared__ float wsum[4];
    if ((t & 63) == 0) wsum[t >> 6] = v;
    __syncthreads();
    if (t == 0)
        atomicAdd(out, ((wsum[0] + wsum[1]) + (wsum[2] + wsum[3])) *
                           (0.5f / (float)(NB * NP)));
}

extern "C" void kernel_launch(void* const* d_in, const int* in_sizes, int n_in,
                              void* d_out, int out_size, void* d_ws, size_t ws_size,
                              hipStream_t stream) {
    const float* pred = (const float*)d_in[0];
    const float* gt   = (const float*)d_in[1];
    float*       out  = (float*)d_out;

    float2*   P  = (float2*)d_ws;                       // 16 * 4096 * 8 B = 512 KB
    unsigned* BS = (unsigned*)(P + (size_t)16 * NP);    // 16 * 4097 * 4 B ≈ 262 KB

    (void)in_sizes; (void)n_in; (void)out_size; (void)ws_size;

    binSort<<<16, 256, 0, stream>>>(pred, gt, P, BS, out);
    binSearch<<<256, 256, 0, stream>>>(P, BS, out);
}